// Round 2
// baseline (106.130 us; speedup 1.0000x reference)
//
#include <hip/hip_runtime.h>

#define QLEN 1024
#define KLEN 1024
#define BSZ 2
#define NHEAD 16
#define DHEAD 64
#define RS 2048            /* BSZ*NHEAD*DHEAD floats per seq row */
#define SCALEF 0.125f
#define BLK_I 32
#define BLK_J 64
#define NJT (KLEN / BLK_J)

typedef __attribute__((ext_vector_type(8))) short s16x8;
typedef __attribute__((ext_vector_type(4))) float f32x4;

__device__ __forceinline__ unsigned short f2bf(float f) {
    union { float f; unsigned int u; } x; x.f = f;
    unsigned int r = x.u + 0x7fffu + ((x.u >> 16) & 1u);
    return (unsigned short)(r >> 16);
}

#define KPAD 72   /* 144B rows: 16B-aligned quads, writes/reads ~conflict-free */
#define VPAD 72
#define PPAD 40   /* 80B rows: 16B-aligned for b128 pf reads */

__global__ __launch_bounds__(256, 4)
void relattn_kernel(const float* __restrict__ q,
                    const float* __restrict__ kh,
                    const float* __restrict__ v,
                    const float* __restrict__ kr,
                    const float* __restrict__ segemb,
                    const float* __restrict__ segmat,
                    const float* __restrict__ rwb,
                    const float* __restrict__ rrb,
                    const float* __restrict__ rsb,
                    const float* __restrict__ mask,
                    float* __restrict__ out)
{
    __shared__ unsigned short KhL[BLK_J][KPAD];
    __shared__ unsigned short KrL[BLK_J][KPAD];
    __shared__ unsigned short VtL[DHEAD][VPAD];   // [d][j], XOR-swizzled 16B granules
    __shared__ unsigned short PlL[4][16][PPAD];   // per-wave P tile (16 x 32)
    __shared__ float ef0s[BLK_I][2];

    // XCD swizzle: round-robin F&7 -> contiguous logical range, so all 32
    // i-blocks of a (b,n) pair share one XCD's L2 (K/V working set ~4MB).
    const int F = blockIdx.x;
    const int L = (F & 7) * 128 + (F >> 3);
    const int it = L & 31;
    const int b  = (L >> 5) & 1;
    const int n  = L >> 6;
    const int i0 = it * BLK_I;

    const int tid  = threadIdx.x;
    const int wave = tid >> 6;
    const int lane = tid & 63;
    const int q4   = lane >> 4;
    const int c    = lane & 15;
    const int ih   = wave >> 1;   // i-half (0/1): rows ih*16..+16
    const int jh   = wave & 1;    // j-half (0/1): cols jh*32..+32 of each tile
    const int boff = b * NHEAD * DHEAD + n * DHEAD;

    // ---- ef0[i][s] = sum_d (q + r_s_bias) * seg_embed[s]  (once) ----
    if (tid < 2 * BLK_I) {
        const int il = tid >> 1;
        const int s  = tid & 1;
        const float* qp2 = q + (size_t)(i0 + il) * RS + boff;
        const float* se  = segemb + (s * NHEAD + n) * DHEAD;
        const float* rs  = rsb + n * DHEAD;
        float a = 0.f;
#pragma unroll
        for (int dd = 0; dd < DHEAD; dd += 4) {
            const f32x4 qv = *(const f32x4*)(qp2 + dd);
            const f32x4 sv = *(const f32x4*)(se + dd);
            const f32x4 rv = *(const f32x4*)(rs + dd);
#pragma unroll
            for (int e = 0; e < 4; ++e) a += (qv[e] + rv[e]) * sv[e];
        }
        ef0s[il][s] = a;
    }

    // ---- Q fragments straight from global (no LDS round-trip) ----
    s16x8 qwf[2], qrf[2];
    {
        const float* qp = q + (size_t)(i0 + ih * 16 + c) * RS + boff;
#pragma unroll
        for (int kk = 0; kk < 2; ++kk) {
            const int off = kk * 32 + q4 * 8;
            const f32x4 q0 = *(const f32x4*)(qp + off);
            const f32x4 q1 = *(const f32x4*)(qp + off + 4);
            const f32x4 w0 = *(const f32x4*)(rwb + n * DHEAD + off);
            const f32x4 w1 = *(const f32x4*)(rwb + n * DHEAD + off + 4);
            const f32x4 r0 = *(const f32x4*)(rrb + n * DHEAD + off);
            const f32x4 r1 = *(const f32x4*)(rrb + n * DHEAD + off + 4);
            s16x8 tw, tr;
#pragma unroll
            for (int e = 0; e < 4; ++e) {
                tw[e]     = (short)f2bf(q0[e] + w0[e]);
                tw[4 + e] = (short)f2bf(q1[e] + w1[e]);
                tr[e]     = (short)f2bf(q0[e] + r0[e]);
                tr[4 + e] = (short)f2bf(q1[e] + r1[e]);
            }
            qwf[kk] = tw;
            qrf[kk] = tr;
        }
    }
    __syncthreads();   // ef0s visible

    float e0[4], e1[4];
    int ig[4];
#pragma unroll
    for (int r = 0; r < 4; ++r) {
        const int iloc = ih * 16 + q4 * 4 + r;
        ig[r] = i0 + iloc;
        e0[r] = ef0s[iloc][0];
        e1[r] = ef0s[iloc][1];
    }

    float m[4], lsum[4];
    f32x4 acc[4];
#pragma unroll
    for (int r = 0; r < 4; ++r) { m[r] = -INFINITY; lsum[r] = 0.f; }
#pragma unroll
    for (int dt = 0; dt < 4; ++dt) acc[dt] = (f32x4)0.f;

    // staging thread mapping
    const int jl = tid >> 2;          // K/Kr: row 0..63
    const int dc = (tid & 3) * 16;    // 16 floats per thread per row
    const int vd = lane;              // V: lane = d, wave covers 16 j rows

    for (int jt = 0; jt < NJT; ++jt) {
        const int j0 = jt * BLK_J;

        // ---- issue all staging loads (in flight across barrier wait) ----
        f32x4 ka[4], ra[4];
        {
            const float* khp = kh + (size_t)(j0 + jl) * RS + boff + dc;
            const float* krp = kr + (size_t)(j0 + jl + 1) * RS + boff + dc; // rel_shift +1
#pragma unroll
            for (int e = 0; e < 4; ++e) {
                ka[e] = *(const f32x4*)(khp + e * 4);
                ra[e] = *(const f32x4*)(krp + e * 4);
            }
        }
        float vv[16];
        {
            const float* vp = v + (size_t)(j0 + wave * 16) * RS + boff + vd;
#pragma unroll
            for (int jj = 0; jj < 16; ++jj) vv[jj] = vp[(size_t)jj * RS];
        }

        __syncthreads();   // B0: all waves done reading previous tile's LDS

        // ---- convert + write LDS ----
        {
            s16x8 h0, h1, r0, r1;
#pragma unroll
            for (int e = 0; e < 4; ++e) {
                h0[e] = (short)f2bf(ka[0][e]); h0[4 + e] = (short)f2bf(ka[1][e]);
                h1[e] = (short)f2bf(ka[2][e]); h1[4 + e] = (short)f2bf(ka[3][e]);
                r0[e] = (short)f2bf(ra[0][e]); r0[4 + e] = (short)f2bf(ra[1][e]);
                r1[e] = (short)f2bf(ra[2][e]); r1[4 + e] = (short)f2bf(ra[3][e]);
            }
            *(s16x8*)&KhL[jl][dc]     = h0;
            *(s16x8*)&KhL[jl][dc + 8] = h1;
            *(s16x8*)&KrL[jl][dc]     = r0;
            *(s16x8*)&KrL[jl][dc + 8] = r1;
        }
#pragma unroll
        for (int gg = 0; gg < 2; ++gg) {
            s16x8 vb;
#pragma unroll
            for (int e = 0; e < 8; ++e) vb[e] = (short)f2bf(vv[gg * 8 + e]);
            const int pg = (wave * 2 + gg) ^ (vd & 7);   // XOR granule swizzle
            *(s16x8*)&VtL[vd][pg * 8] = vb;
        }

        __syncthreads();   // B1: staging visible

        // ---- seg_mat / mask gathers: issue early, consumed in softmax ----
        float2 smv[4][2];
        float  mkv[4][2];
#pragma unroll
        for (int r = 0; r < 4; ++r) {
#pragma unroll
            for (int js = 0; js < 2; ++js) {
                const int jg = j0 + jh * 32 + js * 16 + c;
                const size_t sij = (size_t)ig[r] * KLEN + jg;
                smv[r][js] = *(const float2*)(segmat + sij * (BSZ * 2) + b * 2);
                mkv[r][js] = mask[sij];
            }
        }

        // ---- S = Qw*Kh^T + Qr*Kr^T for this wave's 16x32 quadrant ----
        f32x4 sj[2];
        sj[0] = (f32x4)0.f; sj[1] = (f32x4)0.f;
#pragma unroll
        for (int kk = 0; kk < 2; ++kk) {
#pragma unroll
            for (int js = 0; js < 2; ++js) {
                const s16x8 khf = *(const s16x8*)&KhL[jh * 32 + js * 16 + c][kk * 32 + q4 * 8];
                const s16x8 krf = *(const s16x8*)&KrL[jh * 32 + js * 16 + c][kk * 32 + q4 * 8];
                sj[js] = __builtin_amdgcn_mfma_f32_16x16x32_bf16(qwf[kk], khf, sj[js], 0, 0, 0);
                sj[js] = __builtin_amdgcn_mfma_f32_16x16x32_bf16(qrf[kk], krf, sj[js], 0, 0, 0);
            }
        }

        // ---- epilogue + online softmax (reduce over 16 c-lanes only) ----
        float mt[4];
#pragma unroll
        for (int r = 0; r < 4; ++r) {
#pragma unroll
            for (int js = 0; js < 2; ++js) {
                sj[js][r] = (sj[js][r] + smv[r][js].x * e0[r] + smv[r][js].y * e1[r]) * SCALEF
                            - 1e30f * mkv[r][js];
            }
            mt[r] = fmaxf(sj[0][r], sj[1][r]);
        }
#pragma unroll
        for (int xm = 1; xm <= 8; xm <<= 1) {
#pragma unroll
            for (int r = 0; r < 4; ++r)
                mt[r] = fmaxf(mt[r], __shfl_xor(mt[r], xm, 64));
        }
#pragma unroll
        for (int r = 0; r < 4; ++r) {
            const float mn = fmaxf(m[r], mt[r]);
            const float sc = __expf(m[r] - mn);
            m[r] = mn;
#pragma unroll
            for (int dt = 0; dt < 4; ++dt) acc[dt][r] *= sc;
            float ps = 0.f;
#pragma unroll
            for (int js = 0; js < 2; ++js) {
                const float p = __expf(sj[js][r] - mn);
                ps += p;
                PlL[wave][q4 * 4 + r][js * 16 + c] = f2bf(p);
            }
#pragma unroll
            for (int xm = 1; xm <= 8; xm <<= 1) ps += __shfl_xor(ps, xm, 64);
            lsum[r] = lsum[r] * sc + ps;
        }

        // ---- PV: acc += P(16x32) * V(32x64) ----
        {
            const s16x8 pf = *(const s16x8*)&PlL[wave][c][q4 * 8];
#pragma unroll
            for (int dt = 0; dt < 4; ++dt) {
                const s16x8 vf = *(const s16x8*)&VtL[dt * 16 + c][((jh * 4 + q4) ^ (c & 7)) * 8];
                acc[dt] = __builtin_amdgcn_mfma_f32_16x16x32_bf16(pf, vf, acc[dt], 0, 0, 0);
            }
        }
    }

    // ---- merge wave pairs (jh=0 <- jh=1) and store ----
    __syncthreads();
    float* scrA  = (float*)&KhL[0][0];   // [32][64] partial O from jh=1
    float* scrML = (float*)&VtL[0][0];   // [32][2]  m,l from jh=1
    if (jh == 1) {
#pragma unroll
        for (int r = 0; r < 4; ++r) {
            const int row = ih * 16 + q4 * 4 + r;
#pragma unroll
            for (int dt = 0; dt < 4; ++dt)
                scrA[row * 64 + dt * 16 + c] = acc[dt][r];
            if (c == 0) { scrML[row * 2] = m[r]; scrML[row * 2 + 1] = lsum[r]; }
        }
    }
    __syncthreads();
    if (jh == 0) {
#pragma unroll
        for (int r = 0; r < 4; ++r) {
            const int row = ih * 16 + q4 * 4 + r;
            const float m1 = scrML[row * 2];
            const float l1 = scrML[row * 2 + 1];
            const float M  = fmaxf(m[r], m1);
            const float a0 = __expf(m[r] - M);
            const float a1 = __expf(m1 - M);
            const float inv = 1.f / (lsum[r] * a0 + l1 * a1);
            float* op = out + (size_t)ig[r] * RS + boff;
#pragma unroll
            for (int dt = 0; dt < 4; ++dt)
                op[dt * 16 + c] = (acc[dt][r] * a0 + scrA[row * 64 + dt * 16 + c] * a1) * inv;
        }
    }
}

extern "C" void kernel_launch(void* const* d_in, const int* in_sizes, int n_in,
                              void* d_out, int out_size, void* d_ws, size_t ws_size,
                              hipStream_t stream) {
    const float* q   = (const float*)d_in[0];
    const float* kh  = (const float*)d_in[1];
    const float* v   = (const float*)d_in[2];
    const float* kr  = (const float*)d_in[3];
    const float* se  = (const float*)d_in[4];
    const float* sm  = (const float*)d_in[5];
    const float* rwb = (const float*)d_in[6];
    const float* rrb = (const float*)d_in[7];
    const float* rsb = (const float*)d_in[8];
    const float* msk = (const float*)d_in[9];
    float* out = (float*)d_out;
    const int nblk = (QLEN / BLK_I) * BSZ * NHEAD;   // 1024
    relattn_kernel<<<nblk, 256, 0, stream>>>(q, kh, v, kr, se, sm, rwb, rrb, rsb, msk, out);
}